// Round 1
// baseline (8084.533 us; speedup 1.0000x reference)
//
#include <hip/hip_runtime.h>
#include <math.h>

#define DEVI static __device__ __forceinline__
#define F_INF __builtin_inff()

// ---------------------------------------------------------------------------
// Exactness scheme for kNN top-20 (set semantics — idx feeds max-pools only):
//  * each (split s, wave w) list scans its candidate range in ASCENDING index
//    order and maintains a sorted top-20 with plain strict-< insertion
//    (earlier index wins ties within a list, matching top_k),
//  * the 8 per-query lists are merged with a full (d, idx)-lexicographic
//    tournament (k_merge8) -> global top-20 set == jax.lax.top_k's set.
DEVI bool lexlt(float d, int i, float dr, int ir)
{
    return (d < dr) || (d == dr && i < ir);
}

// plain-< sorted insertion; (INF, any) is a guaranteed no-op.
DEVI void insert20(float* bd, int* bi, float d, int i)
{
#pragma unroll
    for (int j = 19; j >= 1; --j) {
        bool lt  = d < bd[j];
        bool ltp = d < bd[j - 1];
        float nd = ltp ? bd[j - 1] : d;
        int   ni = ltp ? bi[j - 1] : i;
        bd[j] = lt ? nd : bd[j];
        bi[j] = lt ? ni : bi[j];
    }
    bool lt0 = d < bd[0];
    bd[0] = lt0 ? d : bd[0];
    bi[0] = lt0 ? i : bi[0];
}

// Tiered insert: post-warmup inserts land near the tail; if ALL lanes'
// candidates satisfy d >= bd[15] the shift chain only needs positions 16..19
// (the j=16 step's bd[15] compare is statically false). Algebraically
// identical to insert20 in every taken path. INF lanes are no-ops in all tiers.
DEVI void insert_tiered(float* bd, int* bi, float d, int i)
{
    if (__all(!(d < bd[15]))) {
#pragma unroll
        for (int j = 19; j >= 17; --j) {
            bool lt  = d < bd[j];
            bool ltp = d < bd[j - 1];
            float nd = ltp ? bd[j - 1] : d;
            int   ni = ltp ? bi[j - 1] : i;
            bd[j] = lt ? nd : bd[j];
            bi[j] = lt ? ni : bi[j];
        }
        bool lt16 = d < bd[16];
        bd[16] = lt16 ? d : bd[16];
        bi[16] = lt16 ? i : bi[16];
    } else if (__all(!(d < bd[7]))) {
#pragma unroll
        for (int j = 19; j >= 9; --j) {
            bool lt  = d < bd[j];
            bool ltp = d < bd[j - 1];
            float nd = ltp ? bd[j - 1] : d;
            int   ni = ltp ? bi[j - 1] : i;
            bd[j] = lt ? nd : bd[j];
            bi[j] = lt ? ni : bi[j];
        }
        bool lt8 = d < bd[8];
        bd[8] = lt8 ? d : bd[8];
        bi[8] = lt8 ? i : bi[8];
    } else {
        insert20(bd, bi, d, i);
    }
}

DEVI void flushT(float* bd, int* bi, float d, int i, int e, int cnt)
{
    bool want = (e < cnt) && (d < bd[19]);
    if (__any(want))
        insert_tiered(bd, bi, want ? d : F_INF, want ? i : 0x7FFFFFFF);
}

// register append-buffer (cap 4) + wave-coupled flush
#define FLUSH() do { \
    flushT(bd, bi, a0, j0, 0, cnt); \
    flushT(bd, bi, a1, j1, 1, cnt); \
    flushT(bd, bi, a2, j2, 2, cnt); \
    flushT(bd, bi, a3, j3, 3, cnt); \
    cnt = 0; thr = bd[19]; \
} while (0)

#define APPEND(dv, civ) do { \
    bool pass_ = (dv) < thr; \
    if (pass_) { \
        a0 = (cnt == 0) ? (dv) : a0; j0 = (cnt == 0) ? (civ) : j0; \
        a1 = (cnt == 1) ? (dv) : a1; j1 = (cnt == 1) ? (civ) : j1; \
        a2 = (cnt == 2) ? (dv) : a2; j2 = (cnt == 2) ? (civ) : j2; \
        a3 = (cnt == 3) ? (dv) : a3; j3 = (cnt == 3) ? (civ) : j3; \
        ++cnt; \
    } \
    if (__any(cnt == 4)) { FLUSH(); } \
} while (0)

// ---------------------------------------------------------------------------
// K-merge: exact 8-way lex tournament merge of per-(split,wave) sorted lists.
__global__ __launch_bounds__(256) void k_merge8(const float* __restrict__ partD,
                                                const int* __restrict__ partI,
                                                int* __restrict__ idxo)
{
    int q = blockIdx.x * 256 + threadIdx.x;
    const float* rd = partD + (size_t)q * 160;
    const int*   ri = partI + (size_t)q * 160;
    int p0 = 0, p1 = 0, p2 = 0, p3 = 0, p4 = 0, p5 = 0, p6 = 0, p7 = 0;
    int* op = idxo + (size_t)q * 20;
    for (int r = 0; r < 20; ++r) {      // p <= r < 20 at read time: never OOB
        float d0 = rd[p0],        d1 = rd[20 + p1];
        float d2v = rd[40 + p2],  d3 = rd[60 + p3];
        float d4 = rd[80 + p4],   d5 = rd[100 + p5];
        float d6 = rd[120 + p6],  d7 = rd[140 + p7];
        int   i0 = ri[p0],        i1 = ri[20 + p1];
        int   i2 = ri[40 + p2],   i3 = ri[60 + p3];
        int   i4v = ri[80 + p4],  i5 = ri[100 + p5];
        int   i6 = ri[120 + p6],  i7 = ri[140 + p7];
        bool wA = lexlt(d1, i1, d0, i0);   float dA = wA ? d1 : d0; int iA = wA ? i1 : i0; int sA = wA ? 1 : 0;
        bool wB = lexlt(d3, i3, d2v, i2);  float dB = wB ? d3 : d2v; int iB = wB ? i3 : i2; int sB = wB ? 3 : 2;
        bool wC = lexlt(d5, i5, d4, i4v);  float dC = wC ? d5 : d4; int iC = wC ? i5 : i4v; int sC = wC ? 5 : 4;
        bool wD = lexlt(d7, i7, d6, i6);   float dD = wD ? d7 : d6; int iD = wD ? i7 : i6; int sD = wD ? 7 : 6;
        bool wE = lexlt(dB, iB, dA, iA);   float dE = wE ? dB : dA; int iE = wE ? iB : iA; int sE = wE ? sB : sA;
        bool wF = lexlt(dD, iD, dC, iC);   float dF = wF ? dD : dC; int iF = wF ? iD : iC; int sF = wF ? sD : sC;
        bool wG = lexlt(dF, iF, dE, iE);   int ig = wG ? iF : iE;   int sg = wG ? sF : sE;
        op[r] = ig;
        p0 += (sg == 0); p1 += (sg == 1); p2 += (sg == 2); p3 += (sg == 3);
        p4 += (sg == 4); p5 += (sg == 5); p6 += (sg == 6); p7 += (sg == 7);
    }
}

// ---------------------------------------------------------------------------
// K1: exact kNN on 2D points. 1024 blocks = 8 b x 64 qtile x 2 split.
__global__ __launch_bounds__(256, 4) void k_knn2d(const float* __restrict__ x,
                                                  float* __restrict__ partD, int* __restrict__ partI)
{
    __shared__ float2 pts[4096];
    int t = threadIdx.x;
    int blk = blockIdx.x;
    int b = blk >> 7;
    int qt = (blk >> 1) & 63;
    int s = blk & 1;
    const float* xb = x + (size_t)b * 4096 * 2;
    for (int f = t; f < 2048; f += 256)
        ((float4*)pts)[f] = ((const float4*)xb)[f];
    __syncthreads();

    int l = t & 63, w = t >> 6;
    int q = qt * 64 + l;
    float2 qp = pts[q];
    float d2i = qp.x * qp.x + qp.y * qp.y;

    float bd[20]; int bi[20];
#pragma unroll
    for (int j = 0; j < 20; ++j) { bd[j] = F_INF; bi[j] = -1; }
    int cnt = 0; float thr = F_INF;
    float a0 = 0, a1 = 0, a2 = 0, a3 = 0;
    int   j0 = 0, j1 = 0, j2 = 0, j3 = 0;

    int m0 = s * 2048 + w * 512;
    for (int m = m0; m < m0 + 512; ++m) {
        float2 p = pts[m];                       // wave-uniform -> broadcast
        float d2j = p.x * p.x + p.y * p.y;
        float dot = qp.x * p.x + qp.y * p.y;
        float dist = (d2i + d2j) - 2.0f * dot;
        APPEND(dist, m);
    }
    FLUSH();

    size_t base = (((size_t)(b * 4096 + q)) * 8 + s * 4 + w) * 20;
#pragma unroll
    for (int k = 0; k < 20; ++k) { partD[base + k] = bd[k]; partI[base + k] = bi[k]; }
}

// ---------------------------------------------------------------------------
// K2a: per-point layer-1 decomposition.
__global__ void k_prep1(const float* __restrict__ x, const float* __restrict__ w1,
                        const float* __restrict__ b1, float* __restrict__ pm, float* __restrict__ qv)
{
    int tid = blockIdx.x * 256 + threadIdx.x;   // 8*4096*64
    int n = tid >> 6, i = tid & 63;
    float x0 = x[(size_t)n * 2], x1v = x[(size_t)n * 2 + 1];
    float wa = w1[i], wb = w1[64 + i], wc = w1[128 + i], wd = w1[192 + i];
    pm[tid] = fmaf(x0, wa - wc, fmaf(x1v, wb - wd, b1[i]));
    qv[tid] = fmaf(x0, wc, x1v * wd);
}

// ---------------------------------------------------------------------------
// K2: EdgeConv-1 main. 20-lane groups: 3 points per wave (60/64 lanes active),
// 12 points per 256-thread block. Segmented 5-round shuffle max (offsets
// 16/8/4/2/1 clamped at the group boundary — exact since fmax is idempotent).
__global__ __launch_bounds__(256) void k_edge1(const float* __restrict__ pm, const float* __restrict__ q,
                                               const int* __restrict__ idx1,
                                               const float* __restrict__ w2, const float* __restrict__ b2,
                                               const float* __restrict__ w3, const float* __restrict__ b3,
                                               float* __restrict__ x1, float* __restrict__ d2x1)
{
    int t = threadIdx.x;
    int w = t >> 6, l = t & 63;
    int pg = l / 20;                 // group in wave (3 = idle lanes 60..63)
    int k  = l - pg * 20;
    int n0 = blockIdx.x * 12 + w * 3 + pg;
    bool valid = (l < 60) && (n0 < 32768);
    int n = valid ? n0 : 0;
    int b = n >> 12;
    int j = idx1[(size_t)n * 20 + k];
    const float4* pmr = (const float4*)(pm + (size_t)n * 64);
    const float4* qr  = (const float4*)(q + ((size_t)(b * 4096) + j) * 64);

    float h1[64];
#pragma unroll
    for (int i4 = 0; i4 < 16; ++i4) {
        float4 a = pmr[i4], c = qr[i4];
        h1[i4 * 4 + 0] = fmaxf(a.x + c.x, 0.f);
        h1[i4 * 4 + 1] = fmaxf(a.y + c.y, 0.f);
        h1[i4 * 4 + 2] = fmaxf(a.z + c.z, 0.f);
        h1[i4 * 4 + 3] = fmaxf(a.w + c.w, 0.f);
    }
    float h2[64];
#pragma unroll
    for (int o = 0; o < 64; ++o) h2[o] = b2[o];
#pragma unroll
    for (int i = 0; i < 64; ++i) {
        const float* r = w2 + i * 64;       // wave-uniform -> scalar loads
#pragma unroll
        for (int o = 0; o < 64; ++o) h2[o] = fmaf(h1[i], r[o], h2[o]);
    }
#pragma unroll
    for (int o = 0; o < 64; ++o) h2[o] = fmaxf(h2[o], 0.f);

    float h3[64];
#pragma unroll
    for (int o = 0; o < 64; ++o) h3[o] = b3[o];
#pragma unroll
    for (int i = 0; i < 64; ++i) {
        const float* r = w3 + i * 64;
#pragma unroll
        for (int o = 0; o < 64; ++o) h3[o] = fmaf(h2[i], r[o], h3[o]);
    }

    // segmented max over the 20-lane group
    int s16 = (k + 16 < 20) ? (l + 16) : l;
    int s8  = (k + 8  < 20) ? (l + 8)  : l;
    int s4  = (k + 4  < 20) ? (l + 4)  : l;
    int s2  = (k + 2  < 20) ? (l + 2)  : l;
    int s1  = (k + 1  < 20) ? (l + 1)  : l;
#pragma unroll
    for (int o = 0; o < 64; ++o) {
        float v = h3[o];
        v = fmaxf(v, __shfl(v, s16));
        v = fmaxf(v, __shfl(v, s8));
        v = fmaxf(v, __shfl(v, s4));
        v = fmaxf(v, __shfl(v, s2));
        v = fmaxf(v, __shfl(v, s1));
        h3[o] = v;
    }
    if (valid && k == 0) {
        float d2 = 0.f;
#pragma unroll
        for (int o = 0; o < 64; ++o) d2 += h3[o] * h3[o];
        float4* op = (float4*)(x1 + (size_t)n * 64);
#pragma unroll
        for (int i4 = 0; i4 < 16; ++i4)
            op[i4] = make_float4(h3[i4 * 4], h3[i4 * 4 + 1], h3[i4 * 4 + 2], h3[i4 * 4 + 3]);
        d2x1[n] = d2;
    }
}

// ---------------------------------------------------------------------------
// K3: exact kNN in 64-dim feature space, tiled distance-GEMM + fused top-k.
// 1024 blocks = 8 b x 64 qtile x 2 split; block = 64 q x 2048 cand (32 tiles).
//
// v2 pipeline: separate dist buffer Ds + async-STAGE split (T14):
//   tile T's GEMM overlaps tile T+1's global loads (issued into regs at the
//   top of the GEMM phase; the barrier's memory clobber pins them there),
//   LDS writes of T+1 land after B2. Only 2 barriers per tile:
//     B2: GEMM reads of Cs(T) done  -> write Cs(T+1) regs + write Ds(T)
//     B1: Cs(T+1) and Ds(T) visible -> append reads Ds(T), next GEMM reads Cs
//   The append phase of one wave overlaps the next tile's GEMM of others.
//   Distance arithmetic / scan order / tie-breaking identical to v1.
#define S68 68
__global__ __launch_bounds__(256, 3) void k_knn64(const float* __restrict__ x1,
                                                  const float* __restrict__ d2x1,
                                                  float* __restrict__ partD, int* __restrict__ partI)
{
    __shared__ float smem[3 * 64 * S68 + 128];
    float* Qs  = smem;                  // 64 x 68 queries
    float* Cs  = smem + 64 * S68;       // 64 x 68 candidate tile
    float* Ds  = smem + 2 * 64 * S68;   // 64 x 68 distance tile
    float* d2q = smem + 3 * 64 * S68;   // 64
    float* d2c = d2q + 64;              // 64

    int t  = threadIdx.x;
    int blk = blockIdx.x;
    int bb = blk >> 7;
    int qt = (blk >> 1) & 63;
    int s  = blk & 1;
    int qbase  = bb * 4096 + qt * 64;
    int cstart = s * 2048;

    // stage queries + candidate tile 0
    for (int f = t; f < 1024; f += 256) {
        int qq = f >> 4, dp = f & 15;
        *(float4*)&Qs[qq * S68 + dp * 4] =
            *(const float4*)(x1 + ((size_t)(qbase + qq)) * 64 + dp * 4);
    }
    if (t < 64) d2q[t] = d2x1[qbase + t];
    {
        int cbase0 = bb * 4096 + cstart;
        for (int f = t; f < 1024; f += 256) {
            int cc = f >> 4, dp = f & 15;
            *(float4*)&Cs[cc * S68 + dp * 4] =
                *(const float4*)(x1 + ((size_t)(cbase0 + cc)) * 64 + dp * 4);
        }
        if (t < 64) d2c[t] = d2x1[cbase0 + t];
    }
    __syncthreads();

    int m = t & 15, cb = t >> 4;
    int w = t >> 6, l = t & 63;

    float bd[20]; int bi[20];
#pragma unroll
    for (int j = 0; j < 20; ++j) { bd[j] = F_INF; bi[j] = -1; }
    int cnt = 0; float thr = F_INF;
    float a0 = 0, a1 = 0, a2 = 0, a3 = 0;
    int   j0 = 0, j1 = 0, j2 = 0, j3 = 0;

    float d2qr[4];
#pragma unroll
    for (int i = 0; i < 4; ++i) d2qr[i] = d2q[m + 16 * i];

    for (int T = 0; T < 32; ++T) {
        // prefetch tile T+1 into registers (consumed after B2)
        float4 pf0, pf1, pf2, pf3; float pfd2 = 0.f;
        bool has = (T + 1 < 32);
        if (has) {
            int cb2 = bb * 4096 + cstart + (T + 1) * 64;
            {
                int f = t;        int cc = f >> 4, dp = f & 15;
                pf0 = *(const float4*)(x1 + ((size_t)(cb2 + cc)) * 64 + dp * 4);
            }
            {
                int f = t + 256;  int cc = f >> 4, dp = f & 15;
                pf1 = *(const float4*)(x1 + ((size_t)(cb2 + cc)) * 64 + dp * 4);
            }
            {
                int f = t + 512;  int cc = f >> 4, dp = f & 15;
                pf2 = *(const float4*)(x1 + ((size_t)(cb2 + cc)) * 64 + dp * 4);
            }
            {
                int f = t + 768;  int cc = f >> 4, dp = f & 15;
                pf3 = *(const float4*)(x1 + ((size_t)(cb2 + cc)) * 64 + dp * 4);
            }
            if (t < 64) pfd2 = d2x1[cb2 + t];
        }

        float acc[4][4];
#pragma unroll
        for (int i = 0; i < 4; ++i)
#pragma unroll
            for (int j = 0; j < 4; ++j) acc[i][j] = 0.f;
#pragma unroll
        for (int dc = 0; dc < 16; ++dc) {
            float4 qv[4], cv[4];
#pragma unroll
            for (int i = 0; i < 4; ++i) qv[i] = *(const float4*)&Qs[(m + 16 * i) * S68 + dc * 4];
#pragma unroll
            for (int j = 0; j < 4; ++j) cv[j] = *(const float4*)&Cs[(cb + 16 * j) * S68 + dc * 4];
#pragma unroll
            for (int i = 0; i < 4; ++i)
#pragma unroll
                for (int j = 0; j < 4; ++j) {
                    acc[i][j] = fmaf(qv[i].x, cv[j].x, acc[i][j]);
                    acc[i][j] = fmaf(qv[i].y, cv[j].y, acc[i][j]);
                    acc[i][j] = fmaf(qv[i].z, cv[j].z, acc[i][j]);
                    acc[i][j] = fmaf(qv[i].w, cv[j].w, acc[i][j]);
                }
        }
        float d2cr[4];
#pragma unroll
        for (int j = 0; j < 4; ++j) d2cr[j] = d2c[cb + 16 * j];
        __syncthreads();   // B2: all reads of Cs(T)/d2c(T) done

        if (has) {
            {
                int f = t;        int cc = f >> 4, dp = f & 15;
                *(float4*)&Cs[cc * S68 + dp * 4] = pf0;
            }
            {
                int f = t + 256;  int cc = f >> 4, dp = f & 15;
                *(float4*)&Cs[cc * S68 + dp * 4] = pf1;
            }
            {
                int f = t + 512;  int cc = f >> 4, dp = f & 15;
                *(float4*)&Cs[cc * S68 + dp * 4] = pf2;
            }
            {
                int f = t + 768;  int cc = f >> 4, dp = f & 15;
                *(float4*)&Cs[cc * S68 + dp * 4] = pf3;
            }
            if (t < 64) d2c[t] = pfd2;
        }
#pragma unroll
        for (int i = 0; i < 4; ++i)
#pragma unroll
            for (int j = 0; j < 4; ++j)
                Ds[(m + 16 * i) * S68 + (cb + 16 * j)] =
                    (d2qr[i] + d2cr[j]) - 2.0f * acc[i][j];
        __syncthreads();   // B1: Ds(T) + Cs(T+1) visible

        // top-k: lane l owns query l; wave w owns candidate cols [16w, 16w+16)
        // (append overlaps other waves' GEMM of tile T+1; Ds is next written
        //  only after B2(T+1), which waits for this wave's append to finish)
        const float4* drow = (const float4*)&Ds[l * S68 + w * 16];
        int cib = cstart + T * 64 + w * 16;
#pragma unroll
        for (int j4 = 0; j4 < 4; ++j4) {
            float4 dv = drow[j4];
            int ci = cib + j4 * 4;
            APPEND(dv.x, ci + 0);
            APPEND(dv.y, ci + 1);
            APPEND(dv.z, ci + 2);
            APPEND(dv.w, ci + 3);
        }
    }
    FLUSH();

    size_t base = (((size_t)(qbase + l)) * 8 + s * 4 + w) * 20;
#pragma unroll
    for (int k = 0; k < 20; ++k) { partD[base + k] = bd[k]; partI[base + k] = bi[k]; }
}

// ---------------------------------------------------------------------------
// K4a: EdgeConv-2 full decomposition. T = x1@(Wa-Wb)+b, V = x1@Wb.
__global__ __launch_bounds__(128) void k_prep2(const float* __restrict__ x1, const float* __restrict__ w,
                                               const float* __restrict__ bias,
                                               float* __restrict__ T, float* __restrict__ V)
{
    __shared__ float xs[8][64];
    int o = threadIdx.x;
    int g = blockIdx.x * 8;
    for (int t = threadIdx.x; t < 512; t += 128) xs[t >> 6][t & 63] = x1[(size_t)g * 64 + t];
    __syncthreads();
    float at[8] = {}, av[8] = {};
    for (int i = 0; i < 64; ++i) {
        float wt = w[i * 128 + o], wv = w[(64 + i) * 128 + o];
#pragma unroll
        for (int p = 0; p < 8; ++p) {
            float xv = xs[p][i];
            at[p] = fmaf(xv, wt, at[p]);
            av[p] = fmaf(xv, wv, av[p]);
        }
    }
    float bo = bias[o];
#pragma unroll
    for (int p = 0; p < 8; ++p) {
        T[(size_t)(g + p) * 128 + o] = at[p] - av[p] + bo;
        V[(size_t)(g + p) * 128 + o] = av[p];
    }
}

// K4b: x2[n] = T[n] + max_k V[idx2[n,k]]
__global__ __launch_bounds__(256) void k_edge2(const float* __restrict__ T, const float* __restrict__ V,
                                               const int* __restrict__ idx2, float* __restrict__ x2)
{
    int t = threadIdx.x;
    int p = t >> 5, oc = t & 31;
    int n = blockIdx.x * 8 + p;
    int b = n >> 12;
    const int* ip = idx2 + (size_t)n * 20;
    float4 mx = make_float4(-F_INF, -F_INF, -F_INF, -F_INF);
    for (int k = 0; k < 20; ++k) {
        int j = ip[k];
        float4 v = ((const float4*)(V + ((size_t)(b * 4096) + j) * 128))[oc];
        mx.x = fmaxf(mx.x, v.x); mx.y = fmaxf(mx.y, v.y);
        mx.z = fmaxf(mx.z, v.z); mx.w = fmaxf(mx.w, v.w);
    }
    float4 tv = ((const float4*)(T + (size_t)n * 128))[oc];
    float4 r = make_float4(tv.x + mx.x, tv.y + mx.y, tv.z + mx.z, tv.w + mx.w);
    ((float4*)(x2 + (size_t)n * 128))[oc] = r;
}

// ---------------------------------------------------------------------------
// K5: out = max_n( [x1|x2] @ lin1_w + b ), partial max over 32-point chunks.
__global__ __launch_bounds__(256) void k_lin1max(const float* __restrict__ x1, const float* __restrict__ x2,
                                                 const float* __restrict__ w, const float* __restrict__ bias,
                                                 float* __restrict__ partial)
{
    __shared__ float fs[32][192];
    int blk = blockIdx.x;                 // 0..1023
    int b = blk >> 7, c = blk & 127;
    int base_n = b * 4096 + c * 32;
    for (int t = threadIdx.x; t < 2048; t += 256) {
        int n = t >> 6, i = t & 63;
        fs[n][i] = x1[(size_t)(base_n + n) * 64 + i];
    }
    for (int t = threadIdx.x; t < 4096; t += 256) {
        int n = t >> 7, i = t & 127;
        fs[n][64 + i] = x2[(size_t)(base_n + n) * 128 + i];
    }
    __syncthreads();

    float acc[32][4];
#pragma unroll
    for (int n = 0; n < 32; ++n)
#pragma unroll
        for (int oo = 0; oo < 4; ++oo) acc[n][oo] = 0.f;

    for (int i4 = 0; i4 < 48; ++i4) {
        float wv[4][4];
#pragma unroll
        for (int r = 0; r < 4; ++r)
#pragma unroll
            for (int oo = 0; oo < 4; ++oo)
                wv[r][oo] = w[(size_t)(i4 * 4 + r) * 1024 + oo * 256 + threadIdx.x];
#pragma unroll
        for (int n = 0; n < 32; ++n) {
            float4 f = *(const float4*)&fs[n][i4 * 4];
#pragma unroll
            for (int oo = 0; oo < 4; ++oo) {
                acc[n][oo] = fmaf(f.x, wv[0][oo], acc[n][oo]);
                acc[n][oo] = fmaf(f.y, wv[1][oo], acc[n][oo]);
                acc[n][oo] = fmaf(f.z, wv[2][oo], acc[n][oo]);
                acc[n][oo] = fmaf(f.w, wv[3][oo], acc[n][oo]);
            }
        }
    }
#pragma unroll
    for (int oo = 0; oo < 4; ++oo) {
        int o = oo * 256 + threadIdx.x;
        float m = -F_INF;
#pragma unroll
        for (int n = 0; n < 32; ++n) m = fmaxf(m, acc[n][oo]);
        partial[((size_t)b * 128 + c) * 1024 + o] = m + bias[o];
    }
}

__global__ void k_red(const float* __restrict__ partial, float* __restrict__ pooled)
{
    int t = blockIdx.x * 256 + threadIdx.x;  // 8192
    int b = t >> 10, o = t & 1023;
    float m = -F_INF;
    for (int c = 0; c < 128; ++c) m = fmaxf(m, partial[((size_t)b * 128 + c) * 1024 + o]);
    pooled[t] = m;
}

// ---------------------------------------------------------------------------
// classifier head
__global__ __launch_bounds__(256) void k_fc1(const float* __restrict__ pooled, const float* __restrict__ w,
                                             const float* __restrict__ bias, float* __restrict__ g1)
{
    __shared__ float ps[8 * 1024];
    for (int t = threadIdx.x; t < 8192; t += 256) ps[t] = pooled[t];
    __syncthreads();
    int o = blockIdx.x * 256 + threadIdx.x;   // 0..511
    float acc[8] = {};
    for (int i4 = 0; i4 < 256; ++i4) {
        float w0 = w[(size_t)(i4 * 4 + 0) * 512 + o];
        float w1v = w[(size_t)(i4 * 4 + 1) * 512 + o];
        float w2v = w[(size_t)(i4 * 4 + 2) * 512 + o];
        float w3v = w[(size_t)(i4 * 4 + 3) * 512 + o];
#pragma unroll
        for (int bb = 0; bb < 8; ++bb) {
            float4 f = *(const float4*)&ps[bb * 1024 + i4 * 4];
            acc[bb] = fmaf(f.x, w0, fmaf(f.y, w1v, fmaf(f.z, w2v, fmaf(f.w, w3v, acc[bb]))));
        }
    }
    float bo = bias[o];
#pragma unroll
    for (int bb = 0; bb < 8; ++bb) g1[bb * 512 + o] = fmaxf(acc[bb] + bo, 0.f);
}

__global__ __launch_bounds__(256) void k_fc2(const float* __restrict__ g1, const float* __restrict__ w,
                                             const float* __restrict__ bias, float* __restrict__ g2)
{
    __shared__ float gs[8 * 512];
    for (int t = threadIdx.x; t < 4096; t += 256) gs[t] = g1[t];
    __syncthreads();
    int o = threadIdx.x;                      // 0..255
    float acc[8] = {};
    for (int i4 = 0; i4 < 128; ++i4) {
        float w0 = w[(size_t)(i4 * 4 + 0) * 256 + o];
        float w1v = w[(size_t)(i4 * 4 + 1) * 256 + o];
        float w2v = w[(size_t)(i4 * 4 + 2) * 256 + o];
        float w3v = w[(size_t)(i4 * 4 + 3) * 256 + o];
#pragma unroll
        for (int bb = 0; bb < 8; ++bb) {
            float4 f = *(const float4*)&gs[bb * 512 + i4 * 4];
            acc[bb] = fmaf(f.x, w0, fmaf(f.y, w1v, fmaf(f.z, w2v, fmaf(f.w, w3v, acc[bb]))));
        }
    }
    float bo = bias[o];
#pragma unroll
    for (int bb = 0; bb < 8; ++bb) g2[bb * 256 + o] = fmaxf(acc[bb] + bo, 0.f);
}

__global__ void k_fc3sm(const float* __restrict__ g2, const float* __restrict__ w,
                        const float* __restrict__ bias, float* __restrict__ out)
{
    int t = threadIdx.x;      // 128 = 8 batches x 16 lanes
    int b = t >> 4, l = t & 15;
    float lg = -F_INF;
    if (l < 10) {
        float a = bias[l];
        for (int i = 0; i < 256; ++i) a = fmaf(g2[b * 256 + i], w[i * 10 + l], a);
        lg = a;
    }
    float m = lg;
    m = fmaxf(m, __shfl_xor(m, 1, 16));
    m = fmaxf(m, __shfl_xor(m, 2, 16));
    m = fmaxf(m, __shfl_xor(m, 4, 16));
    m = fmaxf(m, __shfl_xor(m, 8, 16));
    float e = (l < 10) ? expf(lg - m) : 0.f;
    float s = e;
    s += __shfl_xor(s, 1, 16);
    s += __shfl_xor(s, 2, 16);
    s += __shfl_xor(s, 4, 16);
    s += __shfl_xor(s, 8, 16);
    if (l < 10) out[b * 10 + l] = (lg - m) - logf(s);
}

// ---------------------------------------------------------------------------
extern "C" void kernel_launch(void* const* d_in, const int* in_sizes, int n_in,
                              void* d_out, int out_size, void* d_ws, size_t ws_size,
                              hipStream_t stream)
{
    (void)in_sizes; (void)n_in; (void)out_size; (void)ws_size;
    const float* data  = (const float*)d_in[0];
    const float* c1w1  = (const float*)d_in[1];
    const float* c1b1  = (const float*)d_in[2];
    const float* c1w2  = (const float*)d_in[3];
    const float* c1b2  = (const float*)d_in[4];
    const float* c1w3  = (const float*)d_in[5];
    const float* c1b3  = (const float*)d_in[6];
    const float* c2w1  = (const float*)d_in[7];
    const float* c2b1  = (const float*)d_in[8];
    const float* lin1w = (const float*)d_in[9];
    const float* lin1b = (const float*)d_in[10];
    const float* mw1   = (const float*)d_in[11];
    const float* mb1   = (const float*)d_in[12];
    const float* mw2   = (const float*)d_in[13];
    const float* mb2   = (const float*)d_in[14];
    const float* mw3   = (const float*)d_in[15];
    const float* mb3   = (const float*)d_in[16];
    float* ws  = (float*)d_ws;
    int*   wsi = (int*)d_ws;
    float* out = (float*)d_out;

    const size_t OFF_IDX1 = 0;          // 655360 i
    const size_t OFF_IDX2 = 0;          // 655360 i (IDX1 dead by then)
    const size_t OFF_X1   = 655360;     // 2097152 f
    const size_t OFF_D2   = 2752512;    // 32768 f
    const size_t OFF_PM   = 2785280;    // 2097152 f
    const size_t OFF_Q    = 4882432;    // 2097152 f
    const size_t OFF_PD   = 2785280;    // 5242880 f   (knn phases)
    const size_t OFF_PI   = 8028160;    // 5242880 i
    const size_t OFF_T    = 2785280;    // 4194304 f
    const size_t OFF_V    = 6979584;    // 4194304 f
    const size_t OFF_X2   = 11173888;   // 4194304 f
    const size_t OFF_PART = 15368192;   // 1048576 f
    const size_t OFF_POOL = 16416768;   // 8192 f
    const size_t OFF_G1   = 16424960;   // 4096 f
    const size_t OFF_G2   = 16429056;   // 2048 f

    k_knn2d<<<1024, 256, 0, stream>>>(data, ws + OFF_PD, wsi + OFF_PI);
    k_merge8<<<128, 256, 0, stream>>>(ws + OFF_PD, wsi + OFF_PI, wsi + OFF_IDX1);
    k_prep1<<<8192, 256, 0, stream>>>(data, c1w1, c1b1, ws + OFF_PM, ws + OFF_Q);
    k_edge1<<<2731, 256, 0, stream>>>(ws + OFF_PM, ws + OFF_Q, wsi + OFF_IDX1,
                                      c1w2, c1b2, c1w3, c1b3, ws + OFF_X1, ws + OFF_D2);
    k_knn64<<<1024, 256, 0, stream>>>(ws + OFF_X1, ws + OFF_D2, ws + OFF_PD, wsi + OFF_PI);
    k_merge8<<<128, 256, 0, stream>>>(ws + OFF_PD, wsi + OFF_PI, wsi + OFF_IDX2);
    k_prep2<<<4096, 128, 0, stream>>>(ws + OFF_X1, c2w1, c2b1, ws + OFF_T, ws + OFF_V);
    k_edge2<<<4096, 256, 0, stream>>>(ws + OFF_T, ws + OFF_V, wsi + OFF_IDX2, ws + OFF_X2);
    k_lin1max<<<1024, 256, 0, stream>>>(ws + OFF_X1, ws + OFF_X2, lin1w, lin1b, ws + OFF_PART);
    k_red<<<32, 256, 0, stream>>>(ws + OFF_PART, ws + OFF_POOL);
    k_fc1<<<2, 256, 0, stream>>>(ws + OFF_POOL, mw1, mb1, ws + OFF_G1);
    k_fc2<<<1, 256, 0, stream>>>(ws + OFF_G1, mw2, mb2, ws + OFF_G2);
    k_fc3sm<<<1, 128, 0, stream>>>(ws + OFF_G2, mw3, mb3, out);
}

// Round 2
// 1553.776 us; speedup vs baseline: 5.2032x; 5.2032x over previous
//
#include <hip/hip_runtime.h>
#include <math.h>

#define DEVI static __device__ __forceinline__
#define F_INF __builtin_inff()

// ---------------------------------------------------------------------------
// Exactness scheme for kNN top-20 (set semantics — idx feeds max-pools only):
//  * each (split s, wave w) list scans its candidate range in ASCENDING index
//    order and maintains a sorted top-20 with plain strict-< insertion
//    (earlier index wins ties within a list, matching top_k),
//  * the 8 per-query lists are merged with a full (d, idx)-lexicographic
//    tournament (k_merge8) -> global top-20 set == jax.lax.top_k's set.
DEVI bool lexlt(float d, int i, float dr, int ir)
{
    return (d < dr) || (d == dr && i < ir);
}

// plain-< sorted insertion; (INF, any) is a guaranteed no-op.
DEVI void insert20(float* bd, int* bi, float d, int i)
{
#pragma unroll
    for (int j = 19; j >= 1; --j) {
        bool lt  = d < bd[j];
        bool ltp = d < bd[j - 1];
        float nd = ltp ? bd[j - 1] : d;
        int   ni = ltp ? bi[j - 1] : i;
        bd[j] = lt ? nd : bd[j];
        bi[j] = lt ? ni : bi[j];
    }
    bool lt0 = d < bd[0];
    bd[0] = lt0 ? d : bd[0];
    bi[0] = lt0 ? i : bi[0];
}

// Tiered insert: post-warmup inserts land near the tail; if ALL lanes'
// candidates satisfy d >= bd[15] the shift chain only needs positions 16..19
// (the j=16 step's bd[15] compare is statically false). Algebraically
// identical to insert20 in every taken path. INF lanes are no-ops in all tiers.
DEVI void insert_tiered(float* bd, int* bi, float d, int i)
{
    if (__all(!(d < bd[15]))) {
#pragma unroll
        for (int j = 19; j >= 17; --j) {
            bool lt  = d < bd[j];
            bool ltp = d < bd[j - 1];
            float nd = ltp ? bd[j - 1] : d;
            int   ni = ltp ? bi[j - 1] : i;
            bd[j] = lt ? nd : bd[j];
            bi[j] = lt ? ni : bi[j];
        }
        bool lt16 = d < bd[16];
        bd[16] = lt16 ? d : bd[16];
        bi[16] = lt16 ? i : bi[16];
    } else if (__all(!(d < bd[7]))) {
#pragma unroll
        for (int j = 19; j >= 9; --j) {
            bool lt  = d < bd[j];
            bool ltp = d < bd[j - 1];
            float nd = ltp ? bd[j - 1] : d;
            int   ni = ltp ? bi[j - 1] : i;
            bd[j] = lt ? nd : bd[j];
            bi[j] = lt ? ni : bi[j];
        }
        bool lt8 = d < bd[8];
        bd[8] = lt8 ? d : bd[8];
        bi[8] = lt8 ? i : bi[8];
    } else {
        insert20(bd, bi, d, i);
    }
}

DEVI void flushT(float* bd, int* bi, float d, int i, int e, int cnt)
{
    bool want = (e < cnt) && (d < bd[19]);
    if (__any(want))
        insert_tiered(bd, bi, want ? d : F_INF, want ? i : 0x7FFFFFFF);
}

// register append-buffer (cap 4) + wave-coupled flush
#define FLUSH() do { \
    flushT(bd, bi, a0, j0, 0, cnt); \
    flushT(bd, bi, a1, j1, 1, cnt); \
    flushT(bd, bi, a2, j2, 2, cnt); \
    flushT(bd, bi, a3, j3, 3, cnt); \
    cnt = 0; thr = bd[19]; \
} while (0)

#define APPEND(dv, civ) do { \
    bool pass_ = (dv) < thr; \
    if (pass_) { \
        a0 = (cnt == 0) ? (dv) : a0; j0 = (cnt == 0) ? (civ) : j0; \
        a1 = (cnt == 1) ? (dv) : a1; j1 = (cnt == 1) ? (civ) : j1; \
        a2 = (cnt == 2) ? (dv) : a2; j2 = (cnt == 2) ? (civ) : j2; \
        a3 = (cnt == 3) ? (dv) : a3; j3 = (cnt == 3) ? (civ) : j3; \
        ++cnt; \
    } \
    if (__any(cnt == 4)) { FLUSH(); } \
} while (0)

// ---------------------------------------------------------------------------
// K-merge: exact 8-way lex tournament merge of per-(split,wave) sorted lists.
__global__ __launch_bounds__(256) void k_merge8(const float* __restrict__ partD,
                                                const int* __restrict__ partI,
                                                int* __restrict__ idxo)
{
    int q = blockIdx.x * 256 + threadIdx.x;
    const float* rd = partD + (size_t)q * 160;
    const int*   ri = partI + (size_t)q * 160;
    int p0 = 0, p1 = 0, p2 = 0, p3 = 0, p4 = 0, p5 = 0, p6 = 0, p7 = 0;
    int* op = idxo + (size_t)q * 20;
    for (int r = 0; r < 20; ++r) {      // p <= r < 20 at read time: never OOB
        float d0 = rd[p0],        d1 = rd[20 + p1];
        float d2v = rd[40 + p2],  d3 = rd[60 + p3];
        float d4 = rd[80 + p4],   d5 = rd[100 + p5];
        float d6 = rd[120 + p6],  d7 = rd[140 + p7];
        int   i0 = ri[p0],        i1 = ri[20 + p1];
        int   i2 = ri[40 + p2],   i3 = ri[60 + p3];
        int   i4v = ri[80 + p4],  i5 = ri[100 + p5];
        int   i6 = ri[120 + p6],  i7 = ri[140 + p7];
        bool wA = lexlt(d1, i1, d0, i0);   float dA = wA ? d1 : d0; int iA = wA ? i1 : i0; int sA = wA ? 1 : 0;
        bool wB = lexlt(d3, i3, d2v, i2);  float dB = wB ? d3 : d2v; int iB = wB ? i3 : i2; int sB = wB ? 3 : 2;
        bool wC = lexlt(d5, i5, d4, i4v);  float dC = wC ? d5 : d4; int iC = wC ? i5 : i4v; int sC = wC ? 5 : 4;
        bool wD = lexlt(d7, i7, d6, i6);   float dD = wD ? d7 : d6; int iD = wD ? i7 : i6; int sD = wD ? 7 : 6;
        bool wE = lexlt(dB, iB, dA, iA);   float dE = wE ? dB : dA; int iE = wE ? iB : iA; int sE = wE ? sB : sA;
        bool wF = lexlt(dD, iD, dC, iC);   float dF = wF ? dD : dC; int iF = wF ? iD : iC; int sF = wF ? sD : sC;
        bool wG = lexlt(dF, iF, dE, iE);   int ig = wG ? iF : iE;   int sg = wG ? sF : sE;
        op[r] = ig;
        p0 += (sg == 0); p1 += (sg == 1); p2 += (sg == 2); p3 += (sg == 3);
        p4 += (sg == 4); p5 += (sg == 5); p6 += (sg == 6); p7 += (sg == 7);
    }
}

// ---------------------------------------------------------------------------
// K1: exact kNN on 2D points. 1024 blocks = 8 b x 64 qtile x 2 split.
__global__ __launch_bounds__(256, 4) void k_knn2d(const float* __restrict__ x,
                                                  float* __restrict__ partD, int* __restrict__ partI)
{
    __shared__ float2 pts[4096];
    int t = threadIdx.x;
    int blk = blockIdx.x;
    int b = blk >> 7;
    int qt = (blk >> 1) & 63;
    int s = blk & 1;
    const float* xb = x + (size_t)b * 4096 * 2;
    for (int f = t; f < 2048; f += 256)
        ((float4*)pts)[f] = ((const float4*)xb)[f];
    __syncthreads();

    int l = t & 63, w = t >> 6;
    int q = qt * 64 + l;
    float2 qp = pts[q];
    float d2i = qp.x * qp.x + qp.y * qp.y;

    float bd[20]; int bi[20];
#pragma unroll
    for (int j = 0; j < 20; ++j) { bd[j] = F_INF; bi[j] = -1; }
    int cnt = 0; float thr = F_INF;
    float a0 = 0, a1 = 0, a2 = 0, a3 = 0;
    int   j0 = 0, j1 = 0, j2 = 0, j3 = 0;

    int m0 = s * 2048 + w * 512;
    for (int m = m0; m < m0 + 512; ++m) {
        float2 p = pts[m];                       // wave-uniform -> broadcast
        float d2j = p.x * p.x + p.y * p.y;
        float dot = qp.x * p.x + qp.y * p.y;
        float dist = (d2i + d2j) - 2.0f * dot;
        APPEND(dist, m);
    }
    FLUSH();

    size_t base = (((size_t)(b * 4096 + q)) * 8 + s * 4 + w) * 20;
#pragma unroll
    for (int k = 0; k < 20; ++k) { partD[base + k] = bd[k]; partI[base + k] = bi[k]; }
}

// ---------------------------------------------------------------------------
// K2a: per-point layer-1 decomposition.
__global__ void k_prep1(const float* __restrict__ x, const float* __restrict__ w1,
                        const float* __restrict__ b1, float* __restrict__ pm, float* __restrict__ qv)
{
    int tid = blockIdx.x * 256 + threadIdx.x;   // 8*4096*64
    int n = tid >> 6, i = tid & 63;
    float x0 = x[(size_t)n * 2], x1v = x[(size_t)n * 2 + 1];
    float wa = w1[i], wb = w1[64 + i], wc = w1[128 + i], wd = w1[192 + i];
    pm[tid] = fmaf(x0, wa - wc, fmaf(x1v, wb - wd, b1[i]));
    qv[tid] = fmaf(x0, wc, x1v * wd);
}

// ---------------------------------------------------------------------------
// K2: EdgeConv-1 main. 20-lane groups: 3 points per wave (60/64 lanes active),
// 12 points per 256-thread block. Segmented 5-round shuffle max (offsets
// 16/8/4/2/1 clamped at the group boundary — exact since fmax is idempotent).
__global__ __launch_bounds__(256) void k_edge1(const float* __restrict__ pm, const float* __restrict__ q,
                                               const int* __restrict__ idx1,
                                               const float* __restrict__ w2, const float* __restrict__ b2,
                                               const float* __restrict__ w3, const float* __restrict__ b3,
                                               float* __restrict__ x1, float* __restrict__ d2x1)
{
    int t = threadIdx.x;
    int w = t >> 6, l = t & 63;
    int pg = l / 20;                 // group in wave (3 = idle lanes 60..63)
    int k  = l - pg * 20;
    int n0 = blockIdx.x * 12 + w * 3 + pg;
    bool valid = (l < 60) && (n0 < 32768);
    int n = valid ? n0 : 0;
    int b = n >> 12;
    int j = idx1[(size_t)n * 20 + k];
    const float4* pmr = (const float4*)(pm + (size_t)n * 64);
    const float4* qr  = (const float4*)(q + ((size_t)(b * 4096) + j) * 64);

    float h1[64];
#pragma unroll
    for (int i4 = 0; i4 < 16; ++i4) {
        float4 a = pmr[i4], c = qr[i4];
        h1[i4 * 4 + 0] = fmaxf(a.x + c.x, 0.f);
        h1[i4 * 4 + 1] = fmaxf(a.y + c.y, 0.f);
        h1[i4 * 4 + 2] = fmaxf(a.z + c.z, 0.f);
        h1[i4 * 4 + 3] = fmaxf(a.w + c.w, 0.f);
    }
    float h2[64];
#pragma unroll
    for (int o = 0; o < 64; ++o) h2[o] = b2[o];
#pragma unroll
    for (int i = 0; i < 64; ++i) {
        const float* r = w2 + i * 64;       // wave-uniform -> scalar loads
#pragma unroll
        for (int o = 0; o < 64; ++o) h2[o] = fmaf(h1[i], r[o], h2[o]);
    }
#pragma unroll
    for (int o = 0; o < 64; ++o) h2[o] = fmaxf(h2[o], 0.f);

    float h3[64];
#pragma unroll
    for (int o = 0; o < 64; ++o) h3[o] = b3[o];
#pragma unroll
    for (int i = 0; i < 64; ++i) {
        const float* r = w3 + i * 64;
#pragma unroll
        for (int o = 0; o < 64; ++o) h3[o] = fmaf(h2[i], r[o], h3[o]);
    }

    // segmented max over the 20-lane group
    int s16 = (k + 16 < 20) ? (l + 16) : l;
    int s8  = (k + 8  < 20) ? (l + 8)  : l;
    int s4  = (k + 4  < 20) ? (l + 4)  : l;
    int s2  = (k + 2  < 20) ? (l + 2)  : l;
    int s1  = (k + 1  < 20) ? (l + 1)  : l;
#pragma unroll
    for (int o = 0; o < 64; ++o) {
        float v = h3[o];
        v = fmaxf(v, __shfl(v, s16));
        v = fmaxf(v, __shfl(v, s8));
        v = fmaxf(v, __shfl(v, s4));
        v = fmaxf(v, __shfl(v, s2));
        v = fmaxf(v, __shfl(v, s1));
        h3[o] = v;
    }
    if (valid && k == 0) {
        float d2 = 0.f;
#pragma unroll
        for (int o = 0; o < 64; ++o) d2 += h3[o] * h3[o];
        float4* op = (float4*)(x1 + (size_t)n * 64);
#pragma unroll
        for (int i4 = 0; i4 < 16; ++i4)
            op[i4] = make_float4(h3[i4 * 4], h3[i4 * 4 + 1], h3[i4 * 4 + 2], h3[i4 * 4 + 3]);
        d2x1[n] = d2;
    }
}

// ---------------------------------------------------------------------------
// K3: exact kNN in 64-dim feature space, tiled distance-GEMM + fused top-k.
// 1024 blocks = 8 b x 64 qtile x 2 split; block = 64 q x 2048 cand (32 tiles).
//
// v3 pipeline: separate dist buffer Ds -> 2 barriers/tile (vs v1's 4), with
// v1's transient staging idiom (load -> ds_write immediately; NO registers
// held across the GEMM — v2's long-lived prefetch regs caused bd/bi scratch
// spill: 22 GB HBM traffic/dispatch).
//   GEMM(T) reads Cs(T) ; write Ds(T)
//   B1: Ds(T) visible, Cs(T)/d2c(T) reads done
//   stage Cs(T+1)/d2c(T+1) (global-load latency hides under append)
//   append(T) reads Ds(T)
//   B2: Cs(T+1) visible; append done before Ds(T+1) write (after GEMM(T+1))
// Distance arithmetic / scan order / tie-breaking identical to v1.
#define S68 68
__global__ __launch_bounds__(256, 3) void k_knn64(const float* __restrict__ x1,
                                                  const float* __restrict__ d2x1,
                                                  float* __restrict__ partD, int* __restrict__ partI)
{
    __shared__ float smem[3 * 64 * S68 + 128];
    float* Qs  = smem;                  // 64 x 68 queries
    float* Cs  = smem + 64 * S68;       // 64 x 68 candidate tile
    float* Ds  = smem + 2 * 64 * S68;   // 64 x 68 distance tile
    float* d2q = smem + 3 * 64 * S68;   // 64
    float* d2c = d2q + 64;              // 64

    int t  = threadIdx.x;
    int blk = blockIdx.x;
    int bb = blk >> 7;
    int qt = (blk >> 1) & 63;
    int s  = blk & 1;
    int qbase  = bb * 4096 + qt * 64;
    int cstart = s * 2048;

    // stage queries + candidate tile 0
    for (int f = t; f < 1024; f += 256) {
        int qq = f >> 4, dp = f & 15;
        *(float4*)&Qs[qq * S68 + dp * 4] =
            *(const float4*)(x1 + ((size_t)(qbase + qq)) * 64 + dp * 4);
    }
    if (t < 64) d2q[t] = d2x1[qbase + t];
    {
        int cbase0 = bb * 4096 + cstart;
        for (int f = t; f < 1024; f += 256) {
            int cc = f >> 4, dp = f & 15;
            *(float4*)&Cs[cc * S68 + dp * 4] =
                *(const float4*)(x1 + ((size_t)(cbase0 + cc)) * 64 + dp * 4);
        }
        if (t < 64) d2c[t] = d2x1[cbase0 + t];
    }
    __syncthreads();

    int m = t & 15, cb = t >> 4;
    int w = t >> 6, l = t & 63;

    float bd[20]; int bi[20];
#pragma unroll
    for (int j = 0; j < 20; ++j) { bd[j] = F_INF; bi[j] = -1; }
    int cnt = 0; float thr = F_INF;
    float a0 = 0, a1 = 0, a2 = 0, a3 = 0;
    int   j0 = 0, j1 = 0, j2 = 0, j3 = 0;

    float d2qr[4];
#pragma unroll
    for (int i = 0; i < 4; ++i) d2qr[i] = d2q[m + 16 * i];

    for (int T = 0; T < 32; ++T) {
        float acc[4][4];
#pragma unroll
        for (int i = 0; i < 4; ++i)
#pragma unroll
            for (int j = 0; j < 4; ++j) acc[i][j] = 0.f;
#pragma unroll
        for (int dc = 0; dc < 16; ++dc) {
            float4 qv[4], cv[4];
#pragma unroll
            for (int i = 0; i < 4; ++i) qv[i] = *(const float4*)&Qs[(m + 16 * i) * S68 + dc * 4];
#pragma unroll
            for (int j = 0; j < 4; ++j) cv[j] = *(const float4*)&Cs[(cb + 16 * j) * S68 + dc * 4];
#pragma unroll
            for (int i = 0; i < 4; ++i)
#pragma unroll
                for (int j = 0; j < 4; ++j) {
                    acc[i][j] = fmaf(qv[i].x, cv[j].x, acc[i][j]);
                    acc[i][j] = fmaf(qv[i].y, cv[j].y, acc[i][j]);
                    acc[i][j] = fmaf(qv[i].z, cv[j].z, acc[i][j]);
                    acc[i][j] = fmaf(qv[i].w, cv[j].w, acc[i][j]);
                }
        }
        float d2cr[4];
#pragma unroll
        for (int j = 0; j < 4; ++j) d2cr[j] = d2c[cb + 16 * j];

#pragma unroll
        for (int i = 0; i < 4; ++i)
#pragma unroll
            for (int j = 0; j < 4; ++j)
                Ds[(m + 16 * i) * S68 + (cb + 16 * j)] =
                    (d2qr[i] + d2cr[j]) - 2.0f * acc[i][j];
        __syncthreads();   // B1: Ds(T) visible; Cs(T)/d2c(T) reads done

        // stage tile T+1 (transient regs only; latency overlaps append below)
        if (T + 1 < 32) {
            int cb2 = bb * 4096 + cstart + (T + 1) * 64;
            for (int f = t; f < 1024; f += 256) {
                int cc = f >> 4, dp = f & 15;
                *(float4*)&Cs[cc * S68 + dp * 4] =
                    *(const float4*)(x1 + ((size_t)(cb2 + cc)) * 64 + dp * 4);
            }
            if (t < 64) d2c[t] = d2x1[cb2 + t];
        }

        // top-k: lane l owns query l; wave w owns candidate cols [16w, 16w+16)
        const float4* drow = (const float4*)&Ds[l * S68 + w * 16];
        int cib = cstart + T * 64 + w * 16;
#pragma unroll
        for (int j4 = 0; j4 < 4; ++j4) {
            float4 dv = drow[j4];
            int ci = cib + j4 * 4;
            APPEND(dv.x, ci + 0);
            APPEND(dv.y, ci + 1);
            APPEND(dv.z, ci + 2);
            APPEND(dv.w, ci + 3);
        }
        __syncthreads();   // B2: Cs(T+1) visible; Ds(T) reads done
    }
    FLUSH();

    size_t base = (((size_t)(qbase + l)) * 8 + s * 4 + w) * 20;
#pragma unroll
    for (int k = 0; k < 20; ++k) { partD[base + k] = bd[k]; partI[base + k] = bi[k]; }
}

// ---------------------------------------------------------------------------
// K4a: EdgeConv-2 full decomposition. T = x1@(Wa-Wb)+b, V = x1@Wb.
__global__ __launch_bounds__(128) void k_prep2(const float* __restrict__ x1, const float* __restrict__ w,
                                               const float* __restrict__ bias,
                                               float* __restrict__ T, float* __restrict__ V)
{
    __shared__ float xs[8][64];
    int o = threadIdx.x;
    int g = blockIdx.x * 8;
    for (int t = threadIdx.x; t < 512; t += 128) xs[t >> 6][t & 63] = x1[(size_t)g * 64 + t];
    __syncthreads();
    float at[8] = {}, av[8] = {};
    for (int i = 0; i < 64; ++i) {
        float wt = w[i * 128 + o], wv = w[(64 + i) * 128 + o];
#pragma unroll
        for (int p = 0; p < 8; ++p) {
            float xv = xs[p][i];
            at[p] = fmaf(xv, wt, at[p]);
            av[p] = fmaf(xv, wv, av[p]);
        }
    }
    float bo = bias[o];
#pragma unroll
    for (int p = 0; p < 8; ++p) {
        T[(size_t)(g + p) * 128 + o] = at[p] - av[p] + bo;
        V[(size_t)(g + p) * 128 + o] = av[p];
    }
}

// K4b: x2[n] = T[n] + max_k V[idx2[n,k]]
__global__ __launch_bounds__(256) void k_edge2(const float* __restrict__ T, const float* __restrict__ V,
                                               const int* __restrict__ idx2, float* __restrict__ x2)
{
    int t = threadIdx.x;
    int p = t >> 5, oc = t & 31;
    int n = blockIdx.x * 8 + p;
    int b = n >> 12;
    const int* ip = idx2 + (size_t)n * 20;
    float4 mx = make_float4(-F_INF, -F_INF, -F_INF, -F_INF);
    for (int k = 0; k < 20; ++k) {
        int j = ip[k];
        float4 v = ((const float4*)(V + ((size_t)(b * 4096) + j) * 128))[oc];
        mx.x = fmaxf(mx.x, v.x); mx.y = fmaxf(mx.y, v.y);
        mx.z = fmaxf(mx.z, v.z); mx.w = fmaxf(mx.w, v.w);
    }
    float4 tv = ((const float4*)(T + (size_t)n * 128))[oc];
    float4 r = make_float4(tv.x + mx.x, tv.y + mx.y, tv.z + mx.z, tv.w + mx.w);
    ((float4*)(x2 + (size_t)n * 128))[oc] = r;
}

// ---------------------------------------------------------------------------
// K5: out = max_n( [x1|x2] @ lin1_w + b ), partial max over 32-point chunks.
__global__ __launch_bounds__(256) void k_lin1max(const float* __restrict__ x1, const float* __restrict__ x2,
                                                 const float* __restrict__ w, const float* __restrict__ bias,
                                                 float* __restrict__ partial)
{
    __shared__ float fs[32][192];
    int blk = blockIdx.x;                 // 0..1023
    int b = blk >> 7, c = blk & 127;
    int base_n = b * 4096 + c * 32;
    for (int t = threadIdx.x; t < 2048; t += 256) {
        int n = t >> 6, i = t & 63;
        fs[n][i] = x1[(size_t)(base_n + n) * 64 + i];
    }
    for (int t = threadIdx.x; t < 4096; t += 256) {
        int n = t >> 7, i = t & 127;
        fs[n][64 + i] = x2[(size_t)(base_n + n) * 128 + i];
    }
    __syncthreads();

    float acc[32][4];
#pragma unroll
    for (int n = 0; n < 32; ++n)
#pragma unroll
        for (int oo = 0; oo < 4; ++oo) acc[n][oo] = 0.f;

    for (int i4 = 0; i4 < 48; ++i4) {
        float wv[4][4];
#pragma unroll
        for (int r = 0; r < 4; ++r)
#pragma unroll
            for (int oo = 0; oo < 4; ++oo)
                wv[r][oo] = w[(size_t)(i4 * 4 + r) * 1024 + oo * 256 + threadIdx.x];
#pragma unroll
        for (int n = 0; n < 32; ++n) {
            float4 f = *(const float4*)&fs[n][i4 * 4];
#pragma unroll
            for (int oo = 0; oo < 4; ++oo) {
                acc[n][oo] = fmaf(f.x, wv[0][oo], acc[n][oo]);
                acc[n][oo] = fmaf(f.y, wv[1][oo], acc[n][oo]);
                acc[n][oo] = fmaf(f.z, wv[2][oo], acc[n][oo]);
                acc[n][oo] = fmaf(f.w, wv[3][oo], acc[n][oo]);
            }
        }
    }
#pragma unroll
    for (int oo = 0; oo < 4; ++oo) {
        int o = oo * 256 + threadIdx.x;
        float m = -F_INF;
#pragma unroll
        for (int n = 0; n < 32; ++n) m = fmaxf(m, acc[n][oo]);
        partial[((size_t)b * 128 + c) * 1024 + o] = m + bias[o];
    }
}

__global__ void k_red(const float* __restrict__ partial, float* __restrict__ pooled)
{
    int t = blockIdx.x * 256 + threadIdx.x;  // 8192
    int b = t >> 10, o = t & 1023;
    float m = -F_INF;
    for (int c = 0; c < 128; ++c) m = fmaxf(m, partial[((size_t)b * 128 + c) * 1024 + o]);
    pooled[t] = m;
}

// ---------------------------------------------------------------------------
// classifier head
__global__ __launch_bounds__(256) void k_fc1(const float* __restrict__ pooled, const float* __restrict__ w,
                                             const float* __restrict__ bias, float* __restrict__ g1)
{
    __shared__ float ps[8 * 1024];
    for (int t = threadIdx.x; t < 8192; t += 256) ps[t] = pooled[t];
    __syncthreads();
    int o = blockIdx.x * 256 + threadIdx.x;   // 0..511
    float acc[8] = {};
    for (int i4 = 0; i4 < 256; ++i4) {
        float w0 = w[(size_t)(i4 * 4 + 0) * 512 + o];
        float w1v = w[(size_t)(i4 * 4 + 1) * 512 + o];
        float w2v = w[(size_t)(i4 * 4 + 2) * 512 + o];
        float w3v = w[(size_t)(i4 * 4 + 3) * 512 + o];
#pragma unroll
        for (int bb = 0; bb < 8; ++bb) {
            float4 f = *(const float4*)&ps[bb * 1024 + i4 * 4];
            acc[bb] = fmaf(f.x, w0, fmaf(f.y, w1v, fmaf(f.z, w2v, fmaf(f.w, w3v, acc[bb]))));
        }
    }
    float bo = bias[o];
#pragma unroll
    for (int bb = 0; bb < 8; ++bb) g1[bb * 512 + o] = fmaxf(acc[bb] + bo, 0.f);
}

__global__ __launch_bounds__(256) void k_fc2(const float* __restrict__ g1, const float* __restrict__ w,
                                             const float* __restrict__ bias, float* __restrict__ g2)
{
    __shared__ float gs[8 * 512];
    for (int t = threadIdx.x; t < 4096; t += 256) gs[t] = g1[t];
    __syncthreads();
    int o = threadIdx.x;                      // 0..255
    float acc[8] = {};
    for (int i4 = 0; i4 < 128; ++i4) {
        float w0 = w[(size_t)(i4 * 4 + 0) * 256 + o];
        float w1v = w[(size_t)(i4 * 4 + 1) * 256 + o];
        float w2v = w[(size_t)(i4 * 4 + 2) * 256 + o];
        float w3v = w[(size_t)(i4 * 4 + 3) * 256 + o];
#pragma unroll
        for (int bb = 0; bb < 8; ++bb) {
            float4 f = *(const float4*)&gs[bb * 512 + i4 * 4];
            acc[bb] = fmaf(f.x, w0, fmaf(f.y, w1v, fmaf(f.z, w2v, fmaf(f.w, w3v, acc[bb]))));
        }
    }
    float bo = bias[o];
#pragma unroll
    for (int bb = 0; bb < 8; ++bb) g2[bb * 256 + o] = fmaxf(acc[bb] + bo, 0.f);
}

__global__ void k_fc3sm(const float* __restrict__ g2, const float* __restrict__ w,
                        const float* __restrict__ bias, float* __restrict__ out)
{
    int t = threadIdx.x;      // 128 = 8 batches x 16 lanes
    int b = t >> 4, l = t & 15;
    float lg = -F_INF;
    if (l < 10) {
        float a = bias[l];
        for (int i = 0; i < 256; ++i) a = fmaf(g2[b * 256 + i], w[i * 10 + l], a);
        lg = a;
    }
    float m = lg;
    m = fmaxf(m, __shfl_xor(m, 1, 16));
    m = fmaxf(m, __shfl_xor(m, 2, 16));
    m = fmaxf(m, __shfl_xor(m, 4, 16));
    m = fmaxf(m, __shfl_xor(m, 8, 16));
    float e = (l < 10) ? expf(lg - m) : 0.f;
    float s = e;
    s += __shfl_xor(s, 1, 16);
    s += __shfl_xor(s, 2, 16);
    s += __shfl_xor(s, 4, 16);
    s += __shfl_xor(s, 8, 16);
    if (l < 10) out[b * 10 + l] = (lg - m) - logf(s);
}

// ---------------------------------------------------------------------------
extern "C" void kernel_launch(void* const* d_in, const int* in_sizes, int n_in,
                              void* d_out, int out_size, void* d_ws, size_t ws_size,
                              hipStream_t stream)
{
    (void)in_sizes; (void)n_in; (void)out_size; (void)ws_size;
    const float* data  = (const float*)d_in[0];
    const float* c1w1  = (const float*)d_in[1];
    const float* c1b1  = (const float*)d_in[2];
    const float* c1w2  = (const float*)d_in[3];
    const float* c1b2  = (const float*)d_in[4];
    const float* c1w3  = (const float*)d_in[5];
    const float* c1b3  = (const float*)d_in[6];
    const float* c2w1  = (const float*)d_in[7];
    const float* c2b1  = (const float*)d_in[8];
    const float* lin1w = (const float*)d_in[9];
    const float* lin1b = (const float*)d_in[10];
    const float* mw1   = (const float*)d_in[11];
    const float* mb1   = (const float*)d_in[12];
    const float* mw2   = (const float*)d_in[13];
    const float* mb2   = (const float*)d_in[14];
    const float* mw3   = (const float*)d_in[15];
    const float* mb3   = (const float*)d_in[16];
    float* ws  = (float*)d_ws;
    int*   wsi = (int*)d_ws;
    float* out = (float*)d_out;

    const size_t OFF_IDX1 = 0;          // 655360 i
    const size_t OFF_IDX2 = 0;          // 655360 i (IDX1 dead by then)
    const size_t OFF_X1   = 655360;     // 2097152 f
    const size_t OFF_D2   = 2752512;    // 32768 f
    const size_t OFF_PM   = 2785280;    // 2097152 f
    const size_t OFF_Q    = 4882432;    // 2097152 f
    const size_t OFF_PD   = 2785280;    // 5242880 f   (knn phases)
    const size_t OFF_PI   = 8028160;    // 5242880 i
    const size_t OFF_T    = 2785280;    // 4194304 f
    const size_t OFF_V    = 6979584;    // 4194304 f
    const size_t OFF_X2   = 11173888;   // 4194304 f
    const size_t OFF_PART = 15368192;   // 1048576 f
    const size_t OFF_POOL = 16416768;   // 8192 f
    const size_t OFF_G1   = 16424960;   // 4096 f
    const size_t OFF_G2   = 16429056;   // 2048 f

    k_knn2d<<<1024, 256, 0, stream>>>(data, ws + OFF_PD, wsi + OFF_PI);
    k_merge8<<<128, 256, 0, stream>>>(ws + OFF_PD, wsi + OFF_PI, wsi + OFF_IDX1);
    k_prep1<<<8192, 256, 0, stream>>>(data, c1w1, c1b1, ws + OFF_PM, ws + OFF_Q);
    k_edge1<<<2731, 256, 0, stream>>>(ws + OFF_PM, ws + OFF_Q, wsi + OFF_IDX1,
                                      c1w2, c1b2, c1w3, c1b3, ws + OFF_X1, ws + OFF_D2);
    k_knn64<<<1024, 256, 0, stream>>>(ws + OFF_X1, ws + OFF_D2, ws + OFF_PD, wsi + OFF_PI);
    k_merge8<<<128, 256, 0, stream>>>(ws + OFF_PD, wsi + OFF_PI, wsi + OFF_IDX2);
    k_prep2<<<4096, 128, 0, stream>>>(ws + OFF_X1, c2w1, c2b1, ws + OFF_T, ws + OFF_V);
    k_edge2<<<4096, 256, 0, stream>>>(ws + OFF_T, ws + OFF_V, wsi + OFF_IDX2, ws + OFF_X2);
    k_lin1max<<<1024, 256, 0, stream>>>(ws + OFF_X1, ws + OFF_X2, lin1w, lin1b, ws + OFF_PART);
    k_red<<<32, 256, 0, stream>>>(ws + OFF_PART, ws + OFF_POOL);
    k_fc1<<<2, 256, 0, stream>>>(ws + OFF_POOL, mw1, mb1, ws + OFF_G1);
    k_fc2<<<1, 256, 0, stream>>>(ws + OFF_G1, mw2, mb2, ws + OFF_G2);
    k_fc3sm<<<1, 128, 0, stream>>>(ws + OFF_G2, mw3, mb3, out);
}

// Round 3
// 1444.784 us; speedup vs baseline: 5.5957x; 1.0754x over previous
//
#include <hip/hip_runtime.h>
#include <math.h>

#define DEVI static __device__ __forceinline__
#define F_INF __builtin_inff()

// ---------------------------------------------------------------------------
// Exactness scheme for kNN top-20 (set semantics — idx feeds max-pools only):
//  * each (split s, wave w) list scans its candidate range in ASCENDING index
//    order and maintains a sorted top-20 with plain strict-< insertion
//    (earlier index wins ties within a list, matching top_k),
//  * the 8 per-query lists are merged with a full (d, idx)-lexicographic
//    tournament (k_merge8) -> global top-20 set == jax.lax.top_k's set.
DEVI bool lexlt(float d, int i, float dr, int ir)
{
    return (d < dr) || (d == dr && i < ir);
}

// plain-< sorted insertion; (INF, any) is a guaranteed no-op.
DEVI void insert20(float* bd, int* bi, float d, int i)
{
#pragma unroll
    for (int j = 19; j >= 1; --j) {
        bool lt  = d < bd[j];
        bool ltp = d < bd[j - 1];
        float nd = ltp ? bd[j - 1] : d;
        int   ni = ltp ? bi[j - 1] : i;
        bd[j] = lt ? nd : bd[j];
        bi[j] = lt ? ni : bi[j];
    }
    bool lt0 = d < bd[0];
    bd[0] = lt0 ? d : bd[0];
    bi[0] = lt0 ? i : bi[0];
}

// Tiered insert: post-warmup inserts land near the tail; if ALL lanes'
// candidates satisfy d >= bd[15] the shift chain only needs positions 16..19
// (the j=16 step's bd[15] compare is statically false). Algebraically
// identical to insert20 in every taken path. INF lanes are no-ops in all tiers.
DEVI void insert_tiered(float* bd, int* bi, float d, int i)
{
    if (__all(!(d < bd[15]))) {
#pragma unroll
        for (int j = 19; j >= 17; --j) {
            bool lt  = d < bd[j];
            bool ltp = d < bd[j - 1];
            float nd = ltp ? bd[j - 1] : d;
            int   ni = ltp ? bi[j - 1] : i;
            bd[j] = lt ? nd : bd[j];
            bi[j] = lt ? ni : bi[j];
        }
        bool lt16 = d < bd[16];
        bd[16] = lt16 ? d : bd[16];
        bi[16] = lt16 ? i : bi[16];
    } else if (__all(!(d < bd[7]))) {
#pragma unroll
        for (int j = 19; j >= 9; --j) {
            bool lt  = d < bd[j];
            bool ltp = d < bd[j - 1];
            float nd = ltp ? bd[j - 1] : d;
            int   ni = ltp ? bi[j - 1] : i;
            bd[j] = lt ? nd : bd[j];
            bi[j] = lt ? ni : bi[j];
        }
        bool lt8 = d < bd[8];
        bd[8] = lt8 ? d : bd[8];
        bi[8] = lt8 ? i : bi[8];
    } else {
        insert20(bd, bi, d, i);
    }
}

DEVI void flushT(float* bd, int* bi, float d, int i, int e, int cnt)
{
    bool want = (e < cnt) && (d < bd[19]);
    if (__any(want))
        insert_tiered(bd, bi, want ? d : F_INF, want ? i : 0x7FFFFFFF);
}

// register append-buffer (cap 4) + wave-coupled flush
#define FLUSH() do { \
    flushT(bd, bi, a0, j0, 0, cnt); \
    flushT(bd, bi, a1, j1, 1, cnt); \
    flushT(bd, bi, a2, j2, 2, cnt); \
    flushT(bd, bi, a3, j3, 3, cnt); \
    cnt = 0; thr = bd[19]; \
} while (0)

#define APPEND(dv, civ) do { \
    bool pass_ = (dv) < thr; \
    if (pass_) { \
        a0 = (cnt == 0) ? (dv) : a0; j0 = (cnt == 0) ? (civ) : j0; \
        a1 = (cnt == 1) ? (dv) : a1; j1 = (cnt == 1) ? (civ) : j1; \
        a2 = (cnt == 2) ? (dv) : a2; j2 = (cnt == 2) ? (civ) : j2; \
        a3 = (cnt == 3) ? (dv) : a3; j3 = (cnt == 3) ? (civ) : j3; \
        ++cnt; \
    } \
    if (__any(cnt == 4)) { FLUSH(); } \
} while (0)

// ---------------------------------------------------------------------------
// K-merge: exact 8-way lex tournament merge of per-(split,wave) sorted lists.
__global__ __launch_bounds__(256) void k_merge8(const float* __restrict__ partD,
                                                const int* __restrict__ partI,
                                                int* __restrict__ idxo)
{
    int q = blockIdx.x * 256 + threadIdx.x;
    const float* rd = partD + (size_t)q * 160;
    const int*   ri = partI + (size_t)q * 160;
    int p0 = 0, p1 = 0, p2 = 0, p3 = 0, p4 = 0, p5 = 0, p6 = 0, p7 = 0;
    int* op = idxo + (size_t)q * 20;
    for (int r = 0; r < 20; ++r) {      // p <= r < 20 at read time: never OOB
        float d0 = rd[p0],        d1 = rd[20 + p1];
        float d2v = rd[40 + p2],  d3 = rd[60 + p3];
        float d4 = rd[80 + p4],   d5 = rd[100 + p5];
        float d6 = rd[120 + p6],  d7 = rd[140 + p7];
        int   i0 = ri[p0],        i1 = ri[20 + p1];
        int   i2 = ri[40 + p2],   i3 = ri[60 + p3];
        int   i4v = ri[80 + p4],  i5 = ri[100 + p5];
        int   i6 = ri[120 + p6],  i7 = ri[140 + p7];
        bool wA = lexlt(d1, i1, d0, i0);   float dA = wA ? d1 : d0; int iA = wA ? i1 : i0; int sA = wA ? 1 : 0;
        bool wB = lexlt(d3, i3, d2v, i2);  float dB = wB ? d3 : d2v; int iB = wB ? i3 : i2; int sB = wB ? 3 : 2;
        bool wC = lexlt(d5, i5, d4, i4v);  float dC = wC ? d5 : d4; int iC = wC ? i5 : i4v; int sC = wC ? 5 : 4;
        bool wD = lexlt(d7, i7, d6, i6);   float dD = wD ? d7 : d6; int iD = wD ? i7 : i6; int sD = wD ? 7 : 6;
        bool wE = lexlt(dB, iB, dA, iA);   float dE = wE ? dB : dA; int iE = wE ? iB : iA; int sE = wE ? sB : sA;
        bool wF = lexlt(dD, iD, dC, iC);   float dF = wF ? dD : dC; int iF = wF ? iD : iC; int sF = wF ? sD : sC;
        bool wG = lexlt(dF, iF, dE, iE);   int ig = wG ? iF : iE;   int sg = wG ? sF : sE;
        op[r] = ig;
        p0 += (sg == 0); p1 += (sg == 1); p2 += (sg == 2); p3 += (sg == 3);
        p4 += (sg == 4); p5 += (sg == 5); p6 += (sg == 6); p7 += (sg == 7);
    }
}

// ---------------------------------------------------------------------------
// K1: exact kNN on 2D points. 1024 blocks = 8 b x 64 qtile x 2 split.
__global__ __launch_bounds__(256, 4) void k_knn2d(const float* __restrict__ x,
                                                  float* __restrict__ partD, int* __restrict__ partI)
{
    __shared__ float2 pts[4096];
    int t = threadIdx.x;
    int blk = blockIdx.x;
    int b = blk >> 7;
    int qt = (blk >> 1) & 63;
    int s = blk & 1;
    const float* xb = x + (size_t)b * 4096 * 2;
    for (int f = t; f < 2048; f += 256)
        ((float4*)pts)[f] = ((const float4*)xb)[f];
    __syncthreads();

    int l = t & 63, w = t >> 6;
    int q = qt * 64 + l;
    float2 qp = pts[q];
    float d2i = qp.x * qp.x + qp.y * qp.y;

    float bd[20]; int bi[20];
#pragma unroll
    for (int j = 0; j < 20; ++j) { bd[j] = F_INF; bi[j] = -1; }
    int cnt = 0; float thr = F_INF;
    float a0 = 0, a1 = 0, a2 = 0, a3 = 0;
    int   j0 = 0, j1 = 0, j2 = 0, j3 = 0;

    int m0 = s * 2048 + w * 512;
    for (int m = m0; m < m0 + 512; ++m) {
        float2 p = pts[m];                       // wave-uniform -> broadcast
        float d2j = p.x * p.x + p.y * p.y;
        float dot = qp.x * p.x + qp.y * p.y;
        float dist = (d2i + d2j) - 2.0f * dot;
        APPEND(dist, m);
    }
    FLUSH();

    size_t base = (((size_t)(b * 4096 + q)) * 8 + s * 4 + w) * 20;
#pragma unroll
    for (int k = 0; k < 20; ++k) { partD[base + k] = bd[k]; partI[base + k] = bi[k]; }
}

// ---------------------------------------------------------------------------
// K2a: per-point layer-1 decomposition.
__global__ void k_prep1(const float* __restrict__ x, const float* __restrict__ w1,
                        const float* __restrict__ b1, float* __restrict__ pm, float* __restrict__ qv)
{
    int tid = blockIdx.x * 256 + threadIdx.x;   // 8*4096*64
    int n = tid >> 6, i = tid & 63;
    float x0 = x[(size_t)n * 2], x1v = x[(size_t)n * 2 + 1];
    float wa = w1[i], wb = w1[64 + i], wc = w1[128 + i], wd = w1[192 + i];
    pm[tid] = fmaf(x0, wa - wc, fmaf(x1v, wb - wd, b1[i]));
    qv[tid] = fmaf(x0, wc, x1v * wd);
}

// ---------------------------------------------------------------------------
// K2: EdgeConv-1 main. 20-lane groups: 3 points per wave (60/64 lanes active),
// 12 points per 256-thread block. Segmented 5-round shuffle max (offsets
// 16/8/4/2/1 clamped at the group boundary — exact since fmax is idempotent).
__global__ __launch_bounds__(256) void k_edge1(const float* __restrict__ pm, const float* __restrict__ q,
                                               const int* __restrict__ idx1,
                                               const float* __restrict__ w2, const float* __restrict__ b2,
                                               const float* __restrict__ w3, const float* __restrict__ b3,
                                               float* __restrict__ x1, float* __restrict__ d2x1)
{
    int t = threadIdx.x;
    int w = t >> 6, l = t & 63;
    int pg = l / 20;                 // group in wave (3 = idle lanes 60..63)
    int k  = l - pg * 20;
    int n0 = blockIdx.x * 12 + w * 3 + pg;
    bool valid = (l < 60) && (n0 < 32768);
    int n = valid ? n0 : 0;
    int b = n >> 12;
    int j = idx1[(size_t)n * 20 + k];
    const float4* pmr = (const float4*)(pm + (size_t)n * 64);
    const float4* qr  = (const float4*)(q + ((size_t)(b * 4096) + j) * 64);

    float h1[64];
#pragma unroll
    for (int i4 = 0; i4 < 16; ++i4) {
        float4 a = pmr[i4], c = qr[i4];
        h1[i4 * 4 + 0] = fmaxf(a.x + c.x, 0.f);
        h1[i4 * 4 + 1] = fmaxf(a.y + c.y, 0.f);
        h1[i4 * 4 + 2] = fmaxf(a.z + c.z, 0.f);
        h1[i4 * 4 + 3] = fmaxf(a.w + c.w, 0.f);
    }
    float h2[64];
#pragma unroll
    for (int o = 0; o < 64; ++o) h2[o] = b2[o];
#pragma unroll
    for (int i = 0; i < 64; ++i) {
        const float* r = w2 + i * 64;       // wave-uniform -> scalar loads
#pragma unroll
        for (int o = 0; o < 64; ++o) h2[o] = fmaf(h1[i], r[o], h2[o]);
    }
#pragma unroll
    for (int o = 0; o < 64; ++o) h2[o] = fmaxf(h2[o], 0.f);

    float h3[64];
#pragma unroll
    for (int o = 0; o < 64; ++o) h3[o] = b3[o];
#pragma unroll
    for (int i = 0; i < 64; ++i) {
        const float* r = w3 + i * 64;
#pragma unroll
        for (int o = 0; o < 64; ++o) h3[o] = fmaf(h2[i], r[o], h3[o]);
    }

    // segmented max over the 20-lane group
    int s16 = (k + 16 < 20) ? (l + 16) : l;
    int s8  = (k + 8  < 20) ? (l + 8)  : l;
    int s4  = (k + 4  < 20) ? (l + 4)  : l;
    int s2  = (k + 2  < 20) ? (l + 2)  : l;
    int s1  = (k + 1  < 20) ? (l + 1)  : l;
#pragma unroll
    for (int o = 0; o < 64; ++o) {
        float v = h3[o];
        v = fmaxf(v, __shfl(v, s16));
        v = fmaxf(v, __shfl(v, s8));
        v = fmaxf(v, __shfl(v, s4));
        v = fmaxf(v, __shfl(v, s2));
        v = fmaxf(v, __shfl(v, s1));
        h3[o] = v;
    }
    if (valid && k == 0) {
        float d2 = 0.f;
#pragma unroll
        for (int o = 0; o < 64; ++o) d2 += h3[o] * h3[o];
        float4* op = (float4*)(x1 + (size_t)n * 64);
#pragma unroll
        for (int i4 = 0; i4 < 16; ++i4)
            op[i4] = make_float4(h3[i4 * 4], h3[i4 * 4 + 1], h3[i4 * 4 + 2], h3[i4 * 4 + 3]);
        d2x1[n] = d2;
    }
}

// ---------------------------------------------------------------------------
// K3: exact kNN in 64-dim feature space, tiled distance-GEMM + fused top-k.
// 1024 blocks = 8 b x 64 qtile x 2 split; block = 64 q x 2048 cand (32 tiles).
//
// v4: BARRIER-FREE k-loop. Column ownership remapped so wave w's GEMM columns
// are exactly its append columns 16w..16w+15:
//   thread (m = l&15, p = l>>4) computes q = m+16i (i=0..3), c = 16w+4p+j.
// Consequences (all LDS deps intra-wave, ordered by the in-order LDS pipe):
//   * wave stages its own 16-row Cs stripe (wave-private writes)
//   * GEMM reads only its own stripe (+ read-only Qs)
//   * dists written into the retired stripe, layout d[c][q] at Crow[c*68+q]
//     (writes: p spreads 16 banks x m consecutive -> 2-way, free;
//      reads: lane-consecutive -> 2-way, free)
//   * append reads its own stripe
// Zero __syncthreads in the 32-tile loop; one initial barrier for Qs/d2q.
// LDS = 35.3 KB -> 4 blocks/CU (16 waves). Candidate sets, scan order, and
// all arithmetic (dc order, xyzw fma order, dist formula) are bitwise
// identical to the v1 lists -> merged output identical.
#define S68 68
__global__ __launch_bounds__(256, 4) void k_knn64(const float* __restrict__ x1,
                                                  const float* __restrict__ d2x1,
                                                  float* __restrict__ partD, int* __restrict__ partI)
{
    __shared__ float smem[2 * 64 * S68 + 128];
    float* Qs   = smem;                 // 64 x 68 queries (read-only after init)
    float* Cs   = smem + 64 * S68;      // 64 x 68 candidates / dist scratch
    float* d2q  = smem + 2 * 64 * S68;  // 64
    float* d2cs = d2q + 64;             // 64 (per-wave 16-entry stripes)

    int t  = threadIdx.x;
    int blk = blockIdx.x;
    int bb = blk >> 7;
    int qt = (blk >> 1) & 63;
    int s  = blk & 1;
    int qbase  = bb * 4096 + qt * 64;
    int cstart = s * 2048;

    for (int f = t; f < 1024; f += 256) {
        int qq = f >> 4, dp = f & 15;
        *(float4*)&Qs[qq * S68 + dp * 4] =
            *(const float4*)(x1 + ((size_t)(qbase + qq)) * 64 + dp * 4);
    }
    if (t < 64) d2q[t] = d2x1[qbase + t];
    __syncthreads();                    // the ONLY block-wide barrier

    int w = t >> 6, l = t & 63;
    int m = l & 15, p = l >> 4;
    float* Crow = Cs + (16 * w) * S68;  // this wave's private stripe

    float bd[20]; int bi[20];
#pragma unroll
    for (int j = 0; j < 20; ++j) { bd[j] = F_INF; bi[j] = -1; }
    int cnt = 0; float thr = F_INF;
    float a0 = 0, a1 = 0, a2 = 0, a3 = 0;
    int   j0 = 0, j1 = 0, j2 = 0, j3 = 0;

    float d2qr[4];
#pragma unroll
    for (int i = 0; i < 4; ++i) d2qr[i] = d2q[m + 16 * i];

    for (int T = 0; T < 32; ++T) {
        int cg = bb * 4096 + cstart + T * 64 + 16 * w;   // global idx of local col 0

        // stage own stripe: 4 x b128 writes, wave touches contiguous 1 KB of x1
#pragma unroll
        for (int r = 0; r < 4; ++r) {
            int rl = 4 * r + p;                          // local col 0..15
            *(float4*)&Crow[rl * S68 + m * 4] =
                *(const float4*)(x1 + ((size_t)(cg + rl)) * 64 + m * 4);
        }
        if (l < 16) d2cs[16 * w + l] = d2x1[cg + l];

        float acc[4][4];
#pragma unroll
        for (int i = 0; i < 4; ++i)
#pragma unroll
            for (int j = 0; j < 4; ++j) acc[i][j] = 0.f;
#pragma unroll
        for (int dc = 0; dc < 16; ++dc) {
            float4 qv[4], cv[4];
#pragma unroll
            for (int i = 0; i < 4; ++i) qv[i] = *(const float4*)&Qs[(m + 16 * i) * S68 + dc * 4];
#pragma unroll
            for (int j = 0; j < 4; ++j) cv[j] = *(const float4*)&Crow[(4 * p + j) * S68 + dc * 4];
#pragma unroll
            for (int i = 0; i < 4; ++i)
#pragma unroll
                for (int j = 0; j < 4; ++j) {
                    acc[i][j] = fmaf(qv[i].x, cv[j].x, acc[i][j]);
                    acc[i][j] = fmaf(qv[i].y, cv[j].y, acc[i][j]);
                    acc[i][j] = fmaf(qv[i].z, cv[j].z, acc[i][j]);
                    acc[i][j] = fmaf(qv[i].w, cv[j].w, acc[i][j]);
                }
        }
        float d2cr[4];
#pragma unroll
        for (int j = 0; j < 4; ++j) d2cr[j] = d2cs[16 * w + 4 * p + j];

        // dists into own retired stripe: d[c][q] at Crow[c*S68 + q]
#pragma unroll
        for (int j = 0; j < 4; ++j)
#pragma unroll
            for (int i = 0; i < 4; ++i)
                Crow[(4 * p + j) * S68 + (m + 16 * i)] =
                    (d2qr[i] + d2cr[j]) - 2.0f * acc[i][j];

        // append: lane l owns query l, cands c = 0..15 ascending (exact order)
        int cib = cstart + T * 64 + 16 * w;
#pragma unroll
        for (int c = 0; c < 16; ++c) {
            float dv = Crow[c * S68 + l];
            APPEND(dv, cib + c);
        }
    }
    FLUSH();

    size_t base = (((size_t)(qbase + l)) * 8 + s * 4 + w) * 20;
#pragma unroll
    for (int k = 0; k < 20; ++k) { partD[base + k] = bd[k]; partI[base + k] = bi[k]; }
}

// ---------------------------------------------------------------------------
// K4a: EdgeConv-2 full decomposition. T = x1@(Wa-Wb)+b, V = x1@Wb.
__global__ __launch_bounds__(128) void k_prep2(const float* __restrict__ x1, const float* __restrict__ w,
                                               const float* __restrict__ bias,
                                               float* __restrict__ T, float* __restrict__ V)
{
    __shared__ float xs[8][64];
    int o = threadIdx.x;
    int g = blockIdx.x * 8;
    for (int t = threadIdx.x; t < 512; t += 128) xs[t >> 6][t & 63] = x1[(size_t)g * 64 + t];
    __syncthreads();
    float at[8] = {}, av[8] = {};
    for (int i = 0; i < 64; ++i) {
        float wt = w[i * 128 + o], wv = w[(64 + i) * 128 + o];
#pragma unroll
        for (int p = 0; p < 8; ++p) {
            float xv = xs[p][i];
            at[p] = fmaf(xv, wt, at[p]);
            av[p] = fmaf(xv, wv, av[p]);
        }
    }
    float bo = bias[o];
#pragma unroll
    for (int p = 0; p < 8; ++p) {
        T[(size_t)(g + p) * 128 + o] = at[p] - av[p] + bo;
        V[(size_t)(g + p) * 128 + o] = av[p];
    }
}

// K4b: x2[n] = T[n] + max_k V[idx2[n,k]]
__global__ __launch_bounds__(256) void k_edge2(const float* __restrict__ T, const float* __restrict__ V,
                                               const int* __restrict__ idx2, float* __restrict__ x2)
{
    int t = threadIdx.x;
    int p = t >> 5, oc = t & 31;
    int n = blockIdx.x * 8 + p;
    int b = n >> 12;
    const int* ip = idx2 + (size_t)n * 20;
    float4 mx = make_float4(-F_INF, -F_INF, -F_INF, -F_INF);
    for (int k = 0; k < 20; ++k) {
        int j = ip[k];
        float4 v = ((const float4*)(V + ((size_t)(b * 4096) + j) * 128))[oc];
        mx.x = fmaxf(mx.x, v.x); mx.y = fmaxf(mx.y, v.y);
        mx.z = fmaxf(mx.z, v.z); mx.w = fmaxf(mx.w, v.w);
    }
    float4 tv = ((const float4*)(T + (size_t)n * 128))[oc];
    float4 r = make_float4(tv.x + mx.x, tv.y + mx.y, tv.z + mx.z, tv.w + mx.w);
    ((float4*)(x2 + (size_t)n * 128))[oc] = r;
}

// ---------------------------------------------------------------------------
// K5: out = max_n( [x1|x2] @ lin1_w + b ), partial max over 32-point chunks.
__global__ __launch_bounds__(256) void k_lin1max(const float* __restrict__ x1, const float* __restrict__ x2,
                                                 const float* __restrict__ w, const float* __restrict__ bias,
                                                 float* __restrict__ partial)
{
    __shared__ float fs[32][192];
    int blk = blockIdx.x;                 // 0..1023
    int b = blk >> 7, c = blk & 127;
    int base_n = b * 4096 + c * 32;
    for (int t = threadIdx.x; t < 2048; t += 256) {
        int n = t >> 6, i = t & 63;
        fs[n][i] = x1[(size_t)(base_n + n) * 64 + i];
    }
    for (int t = threadIdx.x; t < 4096; t += 256) {
        int n = t >> 7, i = t & 127;
        fs[n][64 + i] = x2[(size_t)(base_n + n) * 128 + i];
    }
    __syncthreads();

    float acc[32][4];
#pragma unroll
    for (int n = 0; n < 32; ++n)
#pragma unroll
        for (int oo = 0; oo < 4; ++oo) acc[n][oo] = 0.f;

    for (int i4 = 0; i4 < 48; ++i4) {
        float wv[4][4];
#pragma unroll
        for (int r = 0; r < 4; ++r)
#pragma unroll
            for (int oo = 0; oo < 4; ++oo)
                wv[r][oo] = w[(size_t)(i4 * 4 + r) * 1024 + oo * 256 + threadIdx.x];
#pragma unroll
        for (int n = 0; n < 32; ++n) {
            float4 f = *(const float4*)&fs[n][i4 * 4];
#pragma unroll
            for (int oo = 0; oo < 4; ++oo) {
                acc[n][oo] = fmaf(f.x, wv[0][oo], acc[n][oo]);
                acc[n][oo] = fmaf(f.y, wv[1][oo], acc[n][oo]);
                acc[n][oo] = fmaf(f.z, wv[2][oo], acc[n][oo]);
                acc[n][oo] = fmaf(f.w, wv[3][oo], acc[n][oo]);
            }
        }
    }
#pragma unroll
    for (int oo = 0; oo < 4; ++oo) {
        int o = oo * 256 + threadIdx.x;
        float m = -F_INF;
#pragma unroll
        for (int n = 0; n < 32; ++n) m = fmaxf(m, acc[n][oo]);
        partial[((size_t)b * 128 + c) * 1024 + o] = m + bias[o];
    }
}

__global__ void k_red(const float* __restrict__ partial, float* __restrict__ pooled)
{
    int t = blockIdx.x * 256 + threadIdx.x;  // 8192
    int b = t >> 10, o = t & 1023;
    float m = -F_INF;
    for (int c = 0; c < 128; ++c) m = fmaxf(m, partial[((size_t)b * 128 + c) * 1024 + o]);
    pooled[t] = m;
}

// ---------------------------------------------------------------------------
// classifier head
__global__ __launch_bounds__(256) void k_fc1(const float* __restrict__ pooled, const float* __restrict__ w,
                                             const float* __restrict__ bias, float* __restrict__ g1)
{
    __shared__ float ps[8 * 1024];
    for (int t = threadIdx.x; t < 8192; t += 256) ps[t] = pooled[t];
    __syncthreads();
    int o = blockIdx.x * 256 + threadIdx.x;   // 0..511
    float acc[8] = {};
    for (int i4 = 0; i4 < 256; ++i4) {
        float w0 = w[(size_t)(i4 * 4 + 0) * 512 + o];
        float w1v = w[(size_t)(i4 * 4 + 1) * 512 + o];
        float w2v = w[(size_t)(i4 * 4 + 2) * 512 + o];
        float w3v = w[(size_t)(i4 * 4 + 3) * 512 + o];
#pragma unroll
        for (int bb = 0; bb < 8; ++bb) {
            float4 f = *(const float4*)&ps[bb * 1024 + i4 * 4];
            acc[bb] = fmaf(f.x, w0, fmaf(f.y, w1v, fmaf(f.z, w2v, fmaf(f.w, w3v, acc[bb]))));
        }
    }
    float bo = bias[o];
#pragma unroll
    for (int bb = 0; bb < 8; ++bb) g1[bb * 512 + o] = fmaxf(acc[bb] + bo, 0.f);
}

__global__ __launch_bounds__(256) void k_fc2(const float* __restrict__ g1, const float* __restrict__ w,
                                             const float* __restrict__ bias, float* __restrict__ g2)
{
    __shared__ float gs[8 * 512];
    for (int t = threadIdx.x; t < 4096; t += 256) gs[t] = g1[t];
    __syncthreads();
    int o = threadIdx.x;                      // 0..255
    float acc[8] = {};
    for (int i4 = 0; i4 < 128; ++i4) {
        float w0 = w[(size_t)(i4 * 4 + 0) * 256 + o];
        float w1v = w[(size_t)(i4 * 4 + 1) * 256 + o];
        float w2v = w[(size_t)(i4 * 4 + 2) * 256 + o];
        float w3v = w[(size_t)(i4 * 4 + 3) * 256 + o];
#pragma unroll
        for (int bb = 0; bb < 8; ++bb) {
            float4 f = *(const float4*)&gs[bb * 512 + i4 * 4];
            acc[bb] = fmaf(f.x, w0, fmaf(f.y, w1v, fmaf(f.z, w2v, fmaf(f.w, w3v, acc[bb]))));
        }
    }
    float bo = bias[o];
#pragma unroll
    for (int bb = 0; bb < 8; ++bb) g2[bb * 256 + o] = fmaxf(acc[bb] + bo, 0.f);
}

__global__ void k_fc3sm(const float* __restrict__ g2, const float* __restrict__ w,
                        const float* __restrict__ bias, float* __restrict__ out)
{
    int t = threadIdx.x;      // 128 = 8 batches x 16 lanes
    int b = t >> 4, l = t & 15;
    float lg = -F_INF;
    if (l < 10) {
        float a = bias[l];
        for (int i = 0; i < 256; ++i) a = fmaf(g2[b * 256 + i], w[i * 10 + l], a);
        lg = a;
    }
    float m = lg;
    m = fmaxf(m, __shfl_xor(m, 1, 16));
    m = fmaxf(m, __shfl_xor(m, 2, 16));
    m = fmaxf(m, __shfl_xor(m, 4, 16));
    m = fmaxf(m, __shfl_xor(m, 8, 16));
    float e = (l < 10) ? expf(lg - m) : 0.f;
    float s = e;
    s += __shfl_xor(s, 1, 16);
    s += __shfl_xor(s, 2, 16);
    s += __shfl_xor(s, 4, 16);
    s += __shfl_xor(s, 8, 16);
    if (l < 10) out[b * 10 + l] = (lg - m) - logf(s);
}

// ---------------------------------------------------------------------------
extern "C" void kernel_launch(void* const* d_in, const int* in_sizes, int n_in,
                              void* d_out, int out_size, void* d_ws, size_t ws_size,
                              hipStream_t stream)
{
    (void)in_sizes; (void)n_in; (void)out_size; (void)ws_size;
    const float* data  = (const float*)d_in[0];
    const float* c1w1  = (const float*)d_in[1];
    const float* c1b1  = (const float*)d_in[2];
    const float* c1w2  = (const float*)d_in[3];
    const float* c1b2  = (const float*)d_in[4];
    const float* c1w3  = (const float*)d_in[5];
    const float* c1b3  = (const float*)d_in[6];
    const float* c2w1  = (const float*)d_in[7];
    const float* c2b1  = (const float*)d_in[8];
    const float* lin1w = (const float*)d_in[9];
    const float* lin1b = (const float*)d_in[10];
    const float* mw1   = (const float*)d_in[11];
    const float* mb1   = (const float*)d_in[12];
    const float* mw2   = (const float*)d_in[13];
    const float* mb2   = (const float*)d_in[14];
    const float* mw3   = (const float*)d_in[15];
    const float* mb3   = (const float*)d_in[16];
    float* ws  = (float*)d_ws;
    int*   wsi = (int*)d_ws;
    float* out = (float*)d_out;

    const size_t OFF_IDX1 = 0;          // 655360 i
    const size_t OFF_IDX2 = 0;          // 655360 i (IDX1 dead by then)
    const size_t OFF_X1   = 655360;     // 2097152 f
    const size_t OFF_D2   = 2752512;    // 32768 f
    const size_t OFF_PM   = 2785280;    // 2097152 f
    const size_t OFF_Q    = 4882432;    // 2097152 f
    const size_t OFF_PD   = 2785280;    // 5242880 f   (knn phases)
    const size_t OFF_PI   = 8028160;    // 5242880 i
    const size_t OFF_T    = 2785280;    // 4194304 f
    const size_t OFF_V    = 6979584;    // 4194304 f
    const size_t OFF_X2   = 11173888;   // 4194304 f
    const size_t OFF_PART = 15368192;   // 1048576 f
    const size_t OFF_POOL = 16416768;   // 8192 f
    const size_t OFF_G1   = 16424960;   // 4096 f
    const size_t OFF_G2   = 16429056;   // 2048 f

    k_knn2d<<<1024, 256, 0, stream>>>(data, ws + OFF_PD, wsi + OFF_PI);
    k_merge8<<<128, 256, 0, stream>>>(ws + OFF_PD, wsi + OFF_PI, wsi + OFF_IDX1);
    k_prep1<<<8192, 256, 0, stream>>>(data, c1w1, c1b1, ws + OFF_PM, ws + OFF_Q);
    k_edge1<<<2731, 256, 0, stream>>>(ws + OFF_PM, ws + OFF_Q, wsi + OFF_IDX1,
                                      c1w2, c1b2, c1w3, c1b3, ws + OFF_X1, ws + OFF_D2);
    k_knn64<<<1024, 256, 0, stream>>>(ws + OFF_X1, ws + OFF_D2, ws + OFF_PD, wsi + OFF_PI);
    k_merge8<<<128, 256, 0, stream>>>(ws + OFF_PD, wsi + OFF_PI, wsi + OFF_IDX2);
    k_prep2<<<4096, 128, 0, stream>>>(ws + OFF_X1, c2w1, c2b1, ws + OFF_T, ws + OFF_V);
    k_edge2<<<4096, 256, 0, stream>>>(ws + OFF_T, ws + OFF_V, wsi + OFF_IDX2, ws + OFF_X2);
    k_lin1max<<<1024, 256, 0, stream>>>(ws + OFF_X1, ws + OFF_X2, lin1w, lin1b, ws + OFF_PART);
    k_red<<<32, 256, 0, stream>>>(ws + OFF_PART, ws + OFF_POOL);
    k_fc1<<<2, 256, 0, stream>>>(ws + OFF_POOL, mw1, mb1, ws + OFF_G1);
    k_fc2<<<1, 256, 0, stream>>>(ws + OFF_G1, mw2, mb2, ws + OFF_G2);
    k_fc3sm<<<1, 128, 0, stream>>>(ws + OFF_G2, mw3, mb3, out);
}